// Round 4
// baseline (186.326 us; speedup 1.0000x reference)
//
#include <hip/hip_runtime.h>
#include <hip/hip_bf16.h>
#include <cstdint>

#define BATCH  8192
#define INDIM  1024   // K
#define OUTDIM 2048   // N

typedef float  f32x4   __attribute__((ext_vector_type(4)));
typedef float  f32x16  __attribute__((ext_vector_type(16)));
typedef __bf16 bf16x8  __attribute__((ext_vector_type(8)));
typedef unsigned short u16x8 __attribute__((ext_vector_type(8)));

__device__ __forceinline__ uint16_t f2b(float f) {
    __hip_bfloat16 h = __float2bfloat16(f);
    return __builtin_bit_cast(uint16_t, h);
}

// async global->LDS, 16B per lane. LDS dest is wave-uniform base + lane*16.
__device__ __forceinline__ void async_copy16(const void* g, void* l) {
    __builtin_amdgcn_global_load_lds(
        (__attribute__((address_space(1))) void*)(g),
        (__attribute__((address_space(3))) void*)(l),
        16, 0, 0);
}

// swizzle key: rows 1,8,16 apart all get different keys (restores R2's
// conflict-free lane-collision structure under 32-row fragment reads)
__device__ __forceinline__ int swkey(int r) { return (r ^ (r >> 3)) & 7; }

// ------- prep: P (fp32 [K][O]) -> Pt bf16 [O][K] + psq_part[4][O] -----------
// grid (O/32=64, K/256=4). No atomics: each block owns a (32 o, 256 k) panel
// and writes one psq partial. Epilogue sums the 4 partials.
__global__ __launch_bounds__(256) void prep_p(const float* __restrict__ P,
                                              uint16_t* __restrict__ ptbf,
                                              float* __restrict__ psq_part) {
    __shared__ float tile[64][33];
    __shared__ float psums[32];
    const int tid = threadIdx.x;
    const int o0  = blockIdx.x * 32;
    const int k0  = blockIdx.y * 256;
    const int kk  = tid >> 3;         // 0..31 (load row within half-tile)
    const int oq  = tid & 7;          // 0..7  (float4 col group)
    const int so  = tid >> 3;         // 0..31 (store col)
    const int skc = (tid & 7) * 8;    // 0..56 (store k base)
    float a4[4] = {0.f, 0.f, 0.f, 0.f};
    if (tid < 32) psums[tid] = 0.f;
    for (int st = 0; st < 4; ++st) {
        __syncthreads();   // tile reuse guard (st=0: covers psums init)
#pragma unroll
        for (int r2 = 0; r2 < 2; ++r2) {
            const int k = r2 * 32 + kk;
            const float4 v = *(const float4*)(P + (size_t)(k0 + st * 64 + k) * OUTDIM + o0 + oq * 4);
            tile[k][oq * 4 + 0] = v.x;
            tile[k][oq * 4 + 1] = v.y;
            tile[k][oq * 4 + 2] = v.z;
            tile[k][oq * 4 + 3] = v.w;
            a4[0] += v.x * v.x; a4[1] += v.y * v.y;
            a4[2] += v.z * v.z; a4[3] += v.w * v.w;
        }
        __syncthreads();
        u16x8 w;
#pragma unroll
        for (int j = 0; j < 8; ++j) w[j] = f2b(tile[skc + j][so]);
        *(u16x8*)(ptbf + (size_t)(o0 + so) * INDIM + k0 + st * 64 + skc) = w;
    }
#pragma unroll
    for (int e = 0; e < 4; ++e) atomicAdd(&psums[oq * 4 + e], a4[e]);
    __syncthreads();
    if (tid < 32) psq_part[(size_t)blockIdx.y * OUTDIM + o0 + tid] = psums[tid];
}

// ---------------- main GEMM + epilogue --------------------------------------
// C[m][n] = 2 * sum_k x[m][k] * Pt[n][k] - xsq[m] - psq[n]
// A path: x fp32 loaded directly, converted to bf16 in-register, staged via
// ds_write_b128; x^2 accumulated inline (xsq never materialized).
// B path: ptbf via global_load_lds width=16.
// Tile 128x128, BK=64, 4 waves (2x2), mfma_f32_32x32x16_bf16 2x2 frags.
// LDS slot (r, cs) holds global chunk cs ^ swkey(r).
#define TM 128
#define TN 128
#define BK 64

__global__ __launch_bounds__(256, 3) void gemm_ep(const float* __restrict__ x,
                                                  const uint16_t* __restrict__ ptbf,
                                                  const float* __restrict__ psq_part,
                                                  float* __restrict__ out) {
    __shared__ __align__(16) uint16_t As[TM * BK];
    __shared__ __align__(16) uint16_t Bs[TN * BK];
    __shared__ float xs_tile[TM];

    const int tid  = threadIdx.x;
    const int m0   = blockIdx.x * TM;   // 64 blocks
    const int n0   = blockIdx.y * TN;   // 16 blocks
    const int wave = tid >> 6;
    const int lane = tid & 63;
    const int wm   = (wave >> 1) * 64;
    const int wn   = (wave & 1) * 64;
    const int l31  = lane & 31;
    const int half = lane >> 5;

    // A staging assignment: thread handles row ar, k-half ah (32 fp32/iter)
    const int ar = tid >> 1;            // 0..127
    const int ah = tid & 1;             // 0..1
    const int akey = swkey(ar);
    const float* xrow = x + (size_t)(m0 + ar) * INDIM + ah * 32;
    uint16_t* As_row = As + ar * BK;
    float xs_acc = 0.f;

    f32x16 acc[2][2];
#pragma unroll
    for (int i = 0; i < 2; ++i)
#pragma unroll
        for (int j = 0; j < 2; ++j)
#pragma unroll
            for (int e = 0; e < 16; ++e) acc[i][j][e] = 0.f;

    for (int kb = 0; kb < INDIM; kb += BK) {
        // B staging first: fire-and-forget DMA
#pragma unroll
        for (int t = 0; t < 4; ++t) {
            const int id = t * 256 + tid;       // slot id 0..1023
            const int r  = id >> 3;
            const int cs = id & 7;
            const int cg = cs ^ swkey(r);
            async_copy16(ptbf + (size_t)(n0 + r) * INDIM + kb + cg * 8, Bs + id * 8);
        }
        // A staging: fp32 load -> bf16 -> ds_write (2 passes of 16 floats)
        const float4* src = (const float4*)(xrow + kb);
#pragma unroll
        for (int p = 0; p < 2; ++p) {
            float4 f0 = src[p * 4 + 0];
            float4 f1 = src[p * 4 + 1];
            float4 f2 = src[p * 4 + 2];
            float4 f3 = src[p * 4 + 3];
            xs_acc += f0.x * f0.x + f0.y * f0.y + f0.z * f0.z + f0.w * f0.w
                    + f1.x * f1.x + f1.y * f1.y + f1.z * f1.z + f1.w * f1.w
                    + f2.x * f2.x + f2.y * f2.y + f2.z * f2.z + f2.w * f2.w
                    + f3.x * f3.x + f3.y * f3.y + f3.z * f3.z + f3.w * f3.w;
            u16x8 w0, w1;
            w0[0] = f2b(f0.x); w0[1] = f2b(f0.y); w0[2] = f2b(f0.z); w0[3] = f2b(f0.w);
            w0[4] = f2b(f1.x); w0[5] = f2b(f1.y); w0[6] = f2b(f1.z); w0[7] = f2b(f1.w);
            w1[0] = f2b(f2.x); w1[1] = f2b(f2.y); w1[2] = f2b(f2.z); w1[3] = f2b(f2.w);
            w1[4] = f2b(f3.x); w1[5] = f2b(f3.y); w1[6] = f2b(f3.z); w1[7] = f2b(f3.w);
            const int c0 = ah * 4 + p * 2;
            *(u16x8*)(As_row + ((c0 ^ akey) * 8))       = w0;
            *(u16x8*)(As_row + (((c0 + 1) ^ akey) * 8)) = w1;
        }
        __syncthreads();

#pragma unroll
        for (int ks = 0; ks < 4; ++ks) {        // four K=16 steps
            const int c = ks * 2 + half;        // wanted chunk (8 bf16)
            bf16x8 a[2], b[2];
#pragma unroll
            for (int i = 0; i < 2; ++i) {
                const int r = wm + i * 32 + l31;
                a[i] = *(const bf16x8*)(As + r * BK + (c ^ swkey(r)) * 8);
            }
#pragma unroll
            for (int j = 0; j < 2; ++j) {
                const int r = wn + j * 32 + l31;
                b[j] = *(const bf16x8*)(Bs + r * BK + (c ^ swkey(r)) * 8);
            }
#pragma unroll
            for (int i = 0; i < 2; ++i)
#pragma unroll
                for (int j = 0; j < 2; ++j)
                    acc[i][j] = __builtin_amdgcn_mfma_f32_32x32x16_bf16(a[i], b[j], acc[i][j], 0, 0, 0);
        }
        __syncthreads();
    }

    // xsq: pair-reduce (rows are lane pairs 2j/2j+1 within a wave)
    const float xs2 = xs_acc + __shfl_down(xs_acc, 1);
    if (ah == 0) xs_tile[ar] = xs2;
    __syncthreads();

    // epilogue: C/D layout col = lane&31, row = (reg&3) + 8*(reg>>2) + 4*half
    float ps[2];
#pragma unroll
    for (int j = 0; j < 2; ++j) {
        const int n = n0 + wn + j * 32 + l31;
        ps[j] = psq_part[n] + psq_part[OUTDIM + n] +
                psq_part[2 * OUTDIM + n] + psq_part[3 * OUTDIM + n];
    }
#pragma unroll
    for (int i = 0; i < 2; ++i) {
#pragma unroll
        for (int rg = 0; rg < 16; ++rg) {
            const int rloc = (rg & 3) + 8 * (rg >> 2) + 4 * half;
            const float xs = xs_tile[wm + i * 32 + rloc];
            float* orow = out + (size_t)(m0 + wm + i * 32 + rloc) * OUTDIM + n0 + wn + l31;
#pragma unroll
            for (int j = 0; j < 2; ++j)
                orow[j * 32] = 2.f * acc[i][j][rg] - xs - ps[j];
        }
    }
}

// ---------------- fallback (only if workspace is too small) -----------------
__global__ void fallback_kernel(const float* __restrict__ x,
                                const float* __restrict__ P,
                                float* __restrict__ out) {
    const int o = blockIdx.x * blockDim.x + threadIdx.x;
    const int b = blockIdx.y;
    float cr = 0.f, xq = 0.f, pq = 0.f;
    for (int i = 0; i < INDIM; ++i) {
        const float xv = x[(size_t)b * INDIM + i];
        const float pv = P[(size_t)i * OUTDIM + o];
        cr += xv * pv; xq += xv * xv; pq += pv * pv;
    }
    out[(size_t)b * OUTDIM + o] = 2.f * cr - xq - pq;
}

extern "C" void kernel_launch(void* const* d_in, const int* in_sizes, int n_in,
                              void* d_out, int out_size, void* d_ws, size_t ws_size,
                              hipStream_t stream) {
    (void)in_sizes; (void)n_in; (void)out_size;
    const float* x = (const float*)d_in[0];
    const float* P = (const float*)d_in[1];
    float* out = (float*)d_out;

    const size_t pt_bytes  = (size_t)OUTDIM * INDIM * 2;   // 4 MB
    const size_t psq_bytes = (size_t)4 * OUTDIM * 4;       // 32 KB
    const size_t need = pt_bytes + psq_bytes;

    if (ws_size < need) {
        fallback_kernel<<<dim3(OUTDIM / 256, BATCH), 256, 0, stream>>>(x, P, out);
        return;
    }

    uint16_t* ptbf     = (uint16_t*)d_ws;
    float*    psq_part = (float*)((char*)d_ws + pt_bytes);

    prep_p<<<dim3(OUTDIM / 32, INDIM / 256), 256, 0, stream>>>(P, ptbf, psq_part);
    gemm_ep<<<dim3(BATCH / TM, OUTDIM / TN), 256, 0, stream>>>(x, ptbf, psq_part, out);
}

// Round 5
// 136.147 us; speedup vs baseline: 1.3686x; 1.3686x over previous
//
#include <hip/hip_runtime.h>
#include <hip/hip_bf16.h>
#include <cstdint>

#define BATCH  8192
#define INDIM  1024   // K
#define OUTDIM 2048   // N

typedef float  f32x4   __attribute__((ext_vector_type(4)));
typedef float  f32x16  __attribute__((ext_vector_type(16)));
typedef __bf16 bf16x8  __attribute__((ext_vector_type(8)));
typedef unsigned short u16x4 __attribute__((ext_vector_type(4)));
typedef unsigned short u16x8 __attribute__((ext_vector_type(8)));

__device__ __forceinline__ uint16_t f2b(float f) {
    __hip_bfloat16 h = __float2bfloat16(f);
    return __builtin_bit_cast(uint16_t, h);
}

// async global->LDS, 16B per lane. LDS dest is wave-uniform base + lane*16.
__device__ __forceinline__ void async_copy16(const void* g, void* l) {
    __builtin_amdgcn_global_load_lds(
        (__attribute__((address_space(1))) void*)(g),
        (__attribute__((address_space(3))) void*)(l),
        16, 0, 0);
}

// swizzle key: rows 1, 8, 16 apart all get different keys.
// Measured R4: SQ_LDS_BANK_CONFLICT == 0 with this key under 32-row fragment
// reads (the plain (r&7) key gave a deterministic 4.19e6 with 32x32 mfma).
__device__ __forceinline__ int swkey(int r) { return (r ^ (r >> 3)) & 7; }

// ---------------- prep: x (fp32 [B][K]) -> x_bf16 + x_sq --------------------
// One wave per row, 4 rows per block. (R2 version — measured good.)
__global__ __launch_bounds__(256) void prep_x(const float* __restrict__ x,
                                              uint16_t* __restrict__ xbf,
                                              float* __restrict__ xsq) {
    const int wave = threadIdx.x >> 6;
    const int lane = threadIdx.x & 63;
    const int row  = blockIdx.x * 4 + wave;
    const f32x4* src = (const f32x4*)(x + (size_t)row * INDIM);
    u16x4* dst = (u16x4*)(xbf + (size_t)row * INDIM);
    float s = 0.f;
#pragma unroll
    for (int w = 0; w < 4; ++w) {
        const f32x4 v = src[lane + w * 64];
        s += v.x * v.x + v.y * v.y + v.z * v.z + v.w * v.w;
        u16x4 o;
        o.x = f2b(v.x); o.y = f2b(v.y); o.z = f2b(v.z); o.w = f2b(v.w);
        dst[lane + w * 64] = o;
    }
#pragma unroll
    for (int off = 32; off > 0; off >>= 1) s += __shfl_down(s, off);
    if (lane == 0) xsq[row] = s;
}

// ------- prep: P (fp32 [K][O]) -> Pt bf16 [O][K] + psq_part[4][O] -----------
// grid (O/32=64, K/256=4). No atomics: each block owns a (32 o, 256 k) panel
// and writes one psq partial. Epilogue sums the 4 partials. (R4 version.)
__global__ __launch_bounds__(256) void prep_p(const float* __restrict__ P,
                                              uint16_t* __restrict__ ptbf,
                                              float* __restrict__ psq_part) {
    __shared__ float tile[64][33];
    __shared__ float psums[32];
    const int tid = threadIdx.x;
    const int o0  = blockIdx.x * 32;
    const int k0  = blockIdx.y * 256;
    const int kk  = tid >> 3;         // 0..31 (load row within half-tile)
    const int oq  = tid & 7;          // 0..7  (float4 col group)
    const int so  = tid >> 3;         // 0..31 (store col)
    const int skc = (tid & 7) * 8;    // 0..56 (store k base)
    float a4[4] = {0.f, 0.f, 0.f, 0.f};
    if (tid < 32) psums[tid] = 0.f;
    for (int st = 0; st < 4; ++st) {
        __syncthreads();   // tile reuse guard (st=0: covers psums init)
#pragma unroll
        for (int r2 = 0; r2 < 2; ++r2) {
            const int k = r2 * 32 + kk;
            const float4 v = *(const float4*)(P + (size_t)(k0 + st * 64 + k) * OUTDIM + o0 + oq * 4);
            tile[k][oq * 4 + 0] = v.x;
            tile[k][oq * 4 + 1] = v.y;
            tile[k][oq * 4 + 2] = v.z;
            tile[k][oq * 4 + 3] = v.w;
            a4[0] += v.x * v.x; a4[1] += v.y * v.y;
            a4[2] += v.z * v.z; a4[3] += v.w * v.w;
        }
        __syncthreads();
        u16x8 w;
#pragma unroll
        for (int j = 0; j < 8; ++j) w[j] = f2b(tile[skc + j][so]);
        *(u16x8*)(ptbf + (size_t)(o0 + so) * INDIM + k0 + st * 64 + skc) = w;
    }
#pragma unroll
    for (int e = 0; e < 4; ++e) atomicAdd(&psums[oq * 4 + e], a4[e]);
    __syncthreads();
    if (tid < 32) psq_part[(size_t)blockIdx.y * OUTDIM + o0 + tid] = psums[tid];
}

// ---------------- main GEMM + epilogue --------------------------------------
// C[m][n] = 2 * sum_k A[m][k] * Bt[n][k] - xsq[m] - psq[n]
// Tile 128x128, BK=64, 4 waves (2x2); each wave 64x64 via 2x2 frags of
// mfma_f32_32x32x16_bf16. Both tiles staged via global_load_lds width=16.
// LDS slot (r, cs) holds global chunk cs ^ swkey(r)  -> 0 bank conflicts (R4).
#define TM 128
#define TN 128
#define BK 64

__global__ __launch_bounds__(256) void gemm_ep(const uint16_t* __restrict__ xbf,
                                               const uint16_t* __restrict__ ptbf,
                                               const float* __restrict__ xsq,
                                               const float* __restrict__ psq_part,
                                               float* __restrict__ out) {
    __shared__ __align__(16) uint16_t As[TM * BK];
    __shared__ __align__(16) uint16_t Bs[TN * BK];

    const int tid  = threadIdx.x;
    const int m0   = blockIdx.x * TM;   // 64 blocks
    const int n0   = blockIdx.y * TN;   // 16 blocks
    const int wave = tid >> 6;
    const int lane = tid & 63;
    const int wm   = (wave >> 1) * 64;
    const int wn   = (wave & 1) * 64;
    const int l31  = lane & 31;
    const int half = lane >> 5;

    f32x16 acc[2][2];
#pragma unroll
    for (int i = 0; i < 2; ++i)
#pragma unroll
        for (int j = 0; j < 2; ++j)
#pragma unroll
            for (int e = 0; e < 16; ++e) acc[i][j][e] = 0.f;

    for (int kb = 0; kb < INDIM; kb += BK) {
        // stage A (128x64) and B (128x64); lane sources the XOR'd chunk so
        // slot (r, cs) holds global chunk cs ^ swkey(r)
#pragma unroll
        for (int t = 0; t < 4; ++t) {
            const int id = t * 256 + tid;       // slot id 0..1023
            const int r  = id >> 3;             // tile row
            const int cs = id & 7;              // slot chunk
            const int cg = cs ^ swkey(r);       // global chunk
            async_copy16(xbf  + (size_t)(m0 + r) * INDIM + kb + cg * 8, As + id * 8);
            async_copy16(ptbf + (size_t)(n0 + r) * INDIM + kb + cg * 8, Bs + id * 8);
        }
        __syncthreads();

#pragma unroll
        for (int ks = 0; ks < 4; ++ks) {        // four K=16 steps
            const int c = ks * 2 + half;        // wanted chunk (8 bf16)
            bf16x8 a[2], b[2];
#pragma unroll
            for (int i = 0; i < 2; ++i) {
                const int r = wm + i * 32 + l31;
                a[i] = *(const bf16x8*)(As + r * BK + (c ^ swkey(r)) * 8);
            }
#pragma unroll
            for (int j = 0; j < 2; ++j) {
                const int r = wn + j * 32 + l31;
                b[j] = *(const bf16x8*)(Bs + r * BK + (c ^ swkey(r)) * 8);
            }
#pragma unroll
            for (int i = 0; i < 2; ++i)
#pragma unroll
                for (int j = 0; j < 2; ++j)
                    acc[i][j] = __builtin_amdgcn_mfma_f32_32x32x16_bf16(a[i], b[j], acc[i][j], 0, 0, 0);
        }
        __syncthreads();
    }

    // epilogue: C/D layout col = lane&31, row = (reg&3) + 8*(reg>>2) + 4*half
    const float* xsq_w = xsq + m0 + wm;
    float ps[2];
#pragma unroll
    for (int j = 0; j < 2; ++j) {
        const int n = n0 + wn + j * 32 + l31;
        ps[j] = psq_part[n] + psq_part[OUTDIM + n] +
                psq_part[2 * OUTDIM + n] + psq_part[3 * OUTDIM + n];
    }
#pragma unroll
    for (int i = 0; i < 2; ++i) {
#pragma unroll
        for (int rg = 0; rg < 16; ++rg) {
            const int rloc = (rg & 3) + 8 * (rg >> 2) + 4 * half;
            const float xs = xsq_w[i * 32 + rloc];
            float* orow = out + (size_t)(m0 + wm + i * 32 + rloc) * OUTDIM + n0 + wn + l31;
#pragma unroll
            for (int j = 0; j < 2; ++j)
                orow[j * 32] = 2.f * acc[i][j][rg] - xs - ps[j];
        }
    }
}

// ---------------- fallback (only if workspace is too small) -----------------
__global__ void fallback_kernel(const float* __restrict__ x,
                                const float* __restrict__ P,
                                float* __restrict__ out) {
    const int o = blockIdx.x * blockDim.x + threadIdx.x;
    const int b = blockIdx.y;
    float cr = 0.f, xq = 0.f, pq = 0.f;
    for (int i = 0; i < INDIM; ++i) {
        const float xv = x[(size_t)b * INDIM + i];
        const float pv = P[(size_t)i * OUTDIM + o];
        cr += xv * pv; xq += xv * xv; pq += pv * pv;
    }
    out[(size_t)b * OUTDIM + o] = 2.f * cr - xq - pq;
}

extern "C" void kernel_launch(void* const* d_in, const int* in_sizes, int n_in,
                              void* d_out, int out_size, void* d_ws, size_t ws_size,
                              hipStream_t stream) {
    (void)in_sizes; (void)n_in; (void)out_size;
    const float* x = (const float*)d_in[0];
    const float* P = (const float*)d_in[1];
    float* out = (float*)d_out;

    const size_t xbf_bytes = (size_t)BATCH * INDIM * 2;    // 16 MB
    const size_t pt_bytes  = (size_t)OUTDIM * INDIM * 2;   // 4 MB
    const size_t xsq_bytes = (size_t)BATCH * 4;            // 32 KB
    const size_t psq_bytes = (size_t)4 * OUTDIM * 4;       // 32 KB
    const size_t need = xbf_bytes + pt_bytes + xsq_bytes + psq_bytes;

    if (ws_size < need) {
        fallback_kernel<<<dim3(OUTDIM / 256, BATCH), 256, 0, stream>>>(x, P, out);
        return;
    }

    uint16_t* xbf      = (uint16_t*)d_ws;
    uint16_t* ptbf     = (uint16_t*)((char*)d_ws + xbf_bytes);
    float*    xsq      = (float*)((char*)d_ws + xbf_bytes + pt_bytes);
    float*    psq_part = xsq + BATCH;

    prep_x<<<BATCH / 4, 256, 0, stream>>>(x, xbf, xsq);
    prep_p<<<dim3(OUTDIM / 32, INDIM / 256), 256, 0, stream>>>(P, ptbf, psq_part);
    gemm_ep<<<dim3(BATCH / TM, OUTDIM / TN), 256, 0, stream>>>(xbf, ptbf, xsq, psq_part, out);
}

// Round 6
// 124.999 us; speedup vs baseline: 1.4906x; 1.0892x over previous
//
#include <hip/hip_runtime.h>
#include <hip/hip_bf16.h>
#include <cstdint>

#define BATCH  8192
#define INDIM  1024   // K (elements == bytes in fp8)
#define OUTDIM 2048   // N

typedef float  f32x4   __attribute__((ext_vector_type(4)));
typedef float  f32x16  __attribute__((ext_vector_type(16)));
typedef int    i32x2   __attribute__((ext_vector_type(2)));

// pack 4 floats -> 4 fp8 e4m3 bytes (chip-native format; MFMA consumes same)
__device__ __forceinline__ uint32_t pk_fp8x4(float a, float b, float c, float d) {
    uint32_t v = 0;
    v = __builtin_amdgcn_cvt_pk_fp8_f32(a, b, v, false);  // bytes 0,1
    v = __builtin_amdgcn_cvt_pk_fp8_f32(c, d, v, true);   // bytes 2,3
    return v;
}

// async global->LDS, 16B per lane. LDS dest is wave-uniform base + lane*16.
__device__ __forceinline__ void async_copy16(const void* g, void* l) {
    __builtin_amdgcn_global_load_lds(
        (__attribute__((address_space(1))) void*)(g),
        (__attribute__((address_space(3))) void*)(l),
        16, 0, 0);
}

// 16B-pair swizzle key (fp8 row = 64 B = 4 pairs): rows 1,4 apart differ
__device__ __forceinline__ int k4(int r) { return (r ^ (r >> 2)) & 3; }

// ---------------- prep: x (fp32 [B][K]) -> x_fp8 + x_sq ---------------------
// One wave per row, 4 rows per block. xsq exact fp32.
__global__ __launch_bounds__(256) void prep_x(const float* __restrict__ x,
                                              uint8_t* __restrict__ xq8,
                                              float* __restrict__ xsq) {
    const int wave = threadIdx.x >> 6;
    const int lane = threadIdx.x & 63;
    const int row  = blockIdx.x * 4 + wave;
    const f32x4* src = (const f32x4*)(x + (size_t)row * INDIM);
    uint32_t* dst = (uint32_t*)(xq8 + (size_t)row * INDIM);
    float s = 0.f;
#pragma unroll
    for (int w = 0; w < 4; ++w) {
        const f32x4 v = src[lane + w * 64];
        s += v.x * v.x + v.y * v.y + v.z * v.z + v.w * v.w;
        dst[lane + w * 64] = pk_fp8x4(v.x, v.y, v.z, v.w);
    }
#pragma unroll
    for (int off = 32; off > 0; off >>= 1) s += __shfl_down(s, off);
    if (lane == 0) xsq[row] = s;
}

// ------- prep: P (fp32 [K][O]) -> Pt fp8(32*P) [O][K] + psq_part[4][O] ------
// grid (O/32=64, K/256=4). psq partials computed exact from fp32 P.
// P*32 is a power-of-2 scale (exact); epilogue multiplies acc by 1/16
// (2*cross = 2*acc/32 = acc/16).
__global__ __launch_bounds__(256) void prep_p(const float* __restrict__ P,
                                              uint8_t* __restrict__ pt8,
                                              float* __restrict__ psq_part) {
    __shared__ float tile[64][33];
    __shared__ float psums[32];
    const int tid = threadIdx.x;
    const int o0  = blockIdx.x * 32;
    const int k0  = blockIdx.y * 256;
    const int kk  = tid >> 3;         // 0..31 (load row within half-tile)
    const int oq  = tid & 7;          // 0..7  (float4 col group)
    const int so  = tid >> 3;         // 0..31 (store col)
    const int skc = (tid & 7) * 8;    // 0..56 (store k base)
    float a4[4] = {0.f, 0.f, 0.f, 0.f};
    if (tid < 32) psums[tid] = 0.f;
    for (int st = 0; st < 4; ++st) {
        __syncthreads();   // tile reuse guard (st=0: covers psums init)
#pragma unroll
        for (int r2 = 0; r2 < 2; ++r2) {
            const int k = r2 * 32 + kk;
            const float4 v = *(const float4*)(P + (size_t)(k0 + st * 64 + k) * OUTDIM + o0 + oq * 4);
            tile[k][oq * 4 + 0] = v.x;
            tile[k][oq * 4 + 1] = v.y;
            tile[k][oq * 4 + 2] = v.z;
            tile[k][oq * 4 + 3] = v.w;
            a4[0] += v.x * v.x; a4[1] += v.y * v.y;
            a4[2] += v.z * v.z; a4[3] += v.w * v.w;
        }
        __syncthreads();
        i32x2 w;
        w.x = pk_fp8x4(tile[skc + 0][so] * 32.f, tile[skc + 1][so] * 32.f,
                       tile[skc + 2][so] * 32.f, tile[skc + 3][so] * 32.f);
        w.y = pk_fp8x4(tile[skc + 4][so] * 32.f, tile[skc + 5][so] * 32.f,
                       tile[skc + 6][so] * 32.f, tile[skc + 7][so] * 32.f);
        *(i32x2*)(pt8 + (size_t)(o0 + so) * INDIM + k0 + st * 64 + skc) = w;
    }
#pragma unroll
    for (int e = 0; e < 4; ++e) atomicAdd(&psums[oq * 4 + e], a4[e]);
    __syncthreads();
    if (tid < 32) psq_part[(size_t)blockIdx.y * OUTDIM + o0 + tid] = psums[tid];
}

// ---------------- main GEMM + epilogue --------------------------------------
// C[m][n] = (1/16) * sum_k x8[m][k] * p8[n][k] - xsq[m] - psq[n]
// Tile 128x128, BK=64 bytes (=64 k-elements), 4 waves (2x2); each wave 64x64
// via 2x2 frags of mfma_f32_32x32x16_fp8_fp8 (i64 operands = 8 fp8/lane).
// fp8 halves LDS+cache traffic vs bf16 (the R5 bottleneck).
// LDS 16B-pair p_lds holds global pair p_g = p_lds ^ k4(r).
#define TM 128
#define TN 128
#define BKB 64

__global__ __launch_bounds__(256) void gemm_ep(const uint8_t* __restrict__ xq8,
                                               const uint8_t* __restrict__ pt8,
                                               const float* __restrict__ xsq,
                                               const float* __restrict__ psq_part,
                                               float* __restrict__ out) {
    __shared__ __align__(16) uint8_t As[TM * BKB];   // 8 KB
    __shared__ __align__(16) uint8_t Bs[TN * BKB];   // 8 KB

    const int tid  = threadIdx.x;
    const int m0   = blockIdx.x * TM;   // 64 blocks
    const int n0   = blockIdx.y * TN;   // 16 blocks
    const int wave = tid >> 6;
    const int lane = tid & 63;
    const int wm   = (wave >> 1) * 64;
    const int wn   = (wave & 1) * 64;
    const int l31  = lane & 31;
    const int half = lane >> 5;

    f32x16 acc[2][2];
#pragma unroll
    for (int i = 0; i < 2; ++i)
#pragma unroll
        for (int j = 0; j < 2; ++j)
#pragma unroll
            for (int e = 0; e < 16; ++e) acc[i][j][e] = 0.f;

    for (int kb = 0; kb < INDIM; kb += BKB) {
        // stage A (128x64B) and B (128x64B): 512 slots each, 2+2 per thread
#pragma unroll
        for (int t = 0; t < 2; ++t) {
            const int id = t * 256 + tid;       // slot id 0..511
            const int r  = id >> 2;             // tile row
            const int q  = id & 3;              // 16B pair slot
            const int qg = q ^ k4(r);           // global pair
            async_copy16(xq8 + (size_t)(m0 + r) * INDIM + kb + qg * 16, As + id * 16);
            async_copy16(pt8 + (size_t)(n0 + r) * INDIM + kb + qg * 16, Bs + id * 16);
        }
        __syncthreads();

#pragma unroll
        for (int ks = 0; ks < 4; ++ks) {        // four K=16 steps
            long a[2], b[2];
#pragma unroll
            for (int i = 0; i < 2; ++i) {
                const int r = wm + i * 32 + l31;
                a[i] = *(const long*)(As + r * BKB + (ks ^ k4(r)) * 16 + half * 8);
            }
#pragma unroll
            for (int j = 0; j < 2; ++j) {
                const int r = wn + j * 32 + l31;
                b[j] = *(const long*)(Bs + r * BKB + (ks ^ k4(r)) * 16 + half * 8);
            }
#pragma unroll
            for (int i = 0; i < 2; ++i)
#pragma unroll
                for (int j = 0; j < 2; ++j)
                    acc[i][j] = __builtin_amdgcn_mfma_f32_32x32x16_fp8_fp8(a[i], b[j], acc[i][j], 0, 0, 0);
        }
        __syncthreads();
    }

    // epilogue: C/D layout col = lane&31, row = (reg&3) + 8*(reg>>2) + 4*half
    // (shape-determined, dtype-independent — guide §3). scale: 2*cross = acc/16
    const float* xsq_w = xsq + m0 + wm;
    float ps[2];
#pragma unroll
    for (int j = 0; j < 2; ++j) {
        const int n = n0 + wn + j * 32 + l31;
        ps[j] = psq_part[n] + psq_part[OUTDIM + n] +
                psq_part[2 * OUTDIM + n] + psq_part[3 * OUTDIM + n];
    }
#pragma unroll
    for (int i = 0; i < 2; ++i) {
#pragma unroll
        for (int rg = 0; rg < 16; ++rg) {
            const int rloc = (rg & 3) + 8 * (rg >> 2) + 4 * half;
            const float xs = xsq_w[i * 32 + rloc];
            float* orow = out + (size_t)(m0 + wm + i * 32 + rloc) * OUTDIM + n0 + wn + l31;
#pragma unroll
            for (int j = 0; j < 2; ++j)
                orow[j * 32] = 0.0625f * acc[i][j][rg] - xs - ps[j];
        }
    }
}

// ---------------- fallback (only if workspace is too small) -----------------
__global__ void fallback_kernel(const float* __restrict__ x,
                                const float* __restrict__ P,
                                float* __restrict__ out) {
    const int o = blockIdx.x * blockDim.x + threadIdx.x;
    const int b = blockIdx.y;
    float cr = 0.f, xq = 0.f, pq = 0.f;
    for (int i = 0; i < INDIM; ++i) {
        const float xv = x[(size_t)b * INDIM + i];
        const float pv = P[(size_t)i * OUTDIM + o];
        cr += xv * pv; xq += xv * xv; pq += pv * pv;
    }
    out[(size_t)b * OUTDIM + o] = 2.f * cr - xq - pq;
}

extern "C" void kernel_launch(void* const* d_in, const int* in_sizes, int n_in,
                              void* d_out, int out_size, void* d_ws, size_t ws_size,
                              hipStream_t stream) {
    (void)in_sizes; (void)n_in; (void)out_size;
    const float* x = (const float*)d_in[0];
    const float* P = (const float*)d_in[1];
    float* out = (float*)d_out;

    const size_t xq_bytes  = (size_t)BATCH * INDIM;        // 8 MB
    const size_t pt_bytes  = (size_t)OUTDIM * INDIM;       // 2 MB
    const size_t xsq_bytes = (size_t)BATCH * 4;            // 32 KB
    const size_t psq_bytes = (size_t)4 * OUTDIM * 4;       // 32 KB
    const size_t need = xq_bytes + pt_bytes + xsq_bytes + psq_bytes;

    if (ws_size < need) {
        fallback_kernel<<<dim3(OUTDIM / 256, BATCH), 256, 0, stream>>>(x, P, out);
        return;
    }

    uint8_t* xq8      = (uint8_t*)d_ws;
    uint8_t* pt8      = (uint8_t*)d_ws + xq_bytes;
    float*   xsq      = (float*)((char*)d_ws + xq_bytes + pt_bytes);
    float*   psq_part = xsq + BATCH;

    prep_x<<<BATCH / 4, 256, 0, stream>>>(x, xq8, xsq);
    prep_p<<<dim3(OUTDIM / 32, INDIM / 256), 256, 0, stream>>>(P, pt8, psq_part);
    gemm_ep<<<dim3(BATCH / TM, OUTDIM / TN), 256, 0, stream>>>(xq8, pt8, xsq, psq_part, out);
}